// Round 6
// baseline (4629.967 us; speedup 1.0000x reference)
//
#include <hip/hip_runtime.h>

#define TSTEPS 2048
#define VDIM 128
#define FDIM 512

typedef __attribute__((ext_vector_type(8))) _Float16 half8;
typedef __attribute__((ext_vector_type(4))) _Float16 half4;
typedef __attribute__((ext_vector_type(4))) float floatx4;
typedef unsigned long long u64;

// ws layout (bytes):
//   [0,512K)        WH: f16 hi, frag order [chunk32][kk16][lane64][e8]
//   [512K,1M)       WL: f16 lo*4096, same order
//   [1M,1M+128K)    r parity-0: [g8][kk16][lane64][e8] f16 (16KB/group)
//   [1M+128K,+256K) r parity-1: same
#define WS_WH 0
#define WS_WL (512u * 1024u)
#define WS_R  (1024u * 1024u)

// Pre-swizzle W (fp32 row-major [j][k]) into A-frag order, hi + lo*4096.
// A-frag (16x16x32 f16): lane l holds row (l&15), k = kk*32 + (l>>4)*8 + e.
__global__ __launch_bounds__(256) void rnn_prep(const float* __restrict__ W,
                                                _Float16* __restrict__ WH,
                                                _Float16* __restrict__ WL) {
  int tid = blockIdx.x * 256 + threadIdx.x;   // 32 chunks * 16 kk * 64 lanes
  int c  = tid >> 10;
  int kk = (tid >> 6) & 15;
  int l  = tid & 63;
  int j  = 16 * c + (l & 15);
  int k0 = kk * 32 + (l >> 4) * 8;
  const float* src = W + j * FDIM + k0;
  half8 vh, vl;
#pragma unroll
  for (int e = 0; e < 8; ++e) {
    float w = src[e];
    _Float16 h = (_Float16)w;
    vh[e] = h;
    vl[e] = (_Float16)((w - (float)h) * 4096.0f);
  }
  *(half8*)(WH + (size_t)tid * 8) = vh;
  *(half8*)(WL + (size_t)tid * 8) = vl;
}

__device__ __forceinline__ u64 AL(const char* p) {
  return __hip_atomic_load((const u64*)p, __ATOMIC_RELAXED,
                           __HIP_MEMORY_SCOPE_AGENT);
}

// 32 WGs = 8 row-groups (g) x 4 slices (s), 512 thr = 8 waves.
// Tag-in-data exchange (proven R4): r in B-frag order, step-tag
// tau(t)=(t>>1)&1 in every f16 LSB; consumers poll the data itself via
// IC-coherent loads.  R6: 3-slot rotating poll (period ~ lat/3), WG-local
// features short-circuited through LDS (skip own-store IC round trip),
// launch_bounds(512,1) so the 128 W VGPRs actually stay resident.
__global__ void __launch_bounds__(512, 1)
rnn_main(const float* __restrict__ X, const float* __restrict__ bvec,
         const _Float16* __restrict__ WH, const _Float16* __restrict__ WL,
         _Float16* __restrict__ rbase, float* __restrict__ out) {
  __shared__ _Float16 lds[2][8192];           // 16KB per step-parity
  const int g  = blockIdx.x & 7;
  const int s  = blockIdx.x >> 3;
  const int w  = threadIdx.x >> 6;
  const int l  = threadIdx.x & 63;
  const int lr = l & 15;                      // D col = group-local state row
  const int lg = l >> 4;
  const int c  = 4 * w + s;                   // W chunk = feats [16c,16c+16)
  const int jb = 16 * c + lg * 4;             // this lane's 4 features

  // persistent W fragments (hi + lo): 128 VGPRs, pinned
  half8 wh[16], wl[16];
#pragma unroll
  for (int kk = 0; kk < 16; ++kk) {
    wh[kk] = ((const half8*)WH)[(c * 16 + kk) * 64 + l];
    wl[kk] = ((const half8*)WL)[(c * 16 + kk) * 64 + l];
    asm volatile("" : "+v"(wh[kk]), "+v"(wl[kk]));
  }

  const floatx4 bv = *(const floatx4*)(bvec + jb);
  const bool vis = (16 * c < 128);
  const bool diagHere = (c == g);
  const u64 TAGM = 0x0001000100010001ULL;

  // poll: wave polls exchange chunks 2w (bytes [pc,pc+16)) and 2w+1 (+1024).
  const int pc = (2 * w) * 1024 + l * 16;
  // produced half4 frag offset (halves): kk*512 + (sub*16+lr)*8 + (jb&7)
  const int so = ((jb >> 5) << 9) + ((((jb >> 3) & 3) << 4) + lr) * 8 + (jb & 7);
  // per-lane locality: lane's 16B in chunk 2w covers feat-chunk with
  // c&3 == lg>>1; in chunk 2w+1: c&3 == 2+(lg>>1).  Local => produced by
  // THIS WG (slice s) => arrives via LDS, skip tag check & staging.
  const int loc01 = ((lg >> 1) == s);
  const int loc23 = ((lg >> 1) + 2 == s);

  // zero lds[0] (= r(0) for WG-local features; remote lanes stage over it)
  {
    ulonglong2 z; z.x = 0; z.y = 0;
    ((ulonglong2*)lds[0])[threadIdx.x] = z;
    ((ulonglong2*)lds[0])[512 + threadIdx.x] = z;
  }
  __syncthreads();

  int budget = 4000000;

  for (int t = 0; t < TSTEPS; ++t) {
    const char* rb = (const char*)rbase + (size_t)(t & 1) * (128 * 1024)
                   + (size_t)g * 16384;
    const u64 want = (u64)((t >> 1) & 1) * TAGM;
    u64 v0, v1, v2, v3;
    {
#define OK(x0,x1,x2,x3) __all((loc01 | ((((x0)&TAGM)==want) & (((x1)&TAGM)==want))) \
                            & (loc23 | ((((x2)&TAGM)==want) & (((x3)&TAGM)==want))))
      u64 a0=AL(rb+pc),a1=AL(rb+pc+8),a2=AL(rb+pc+1024),a3=AL(rb+pc+1032);
      u64 b0=AL(rb+pc),b1=AL(rb+pc+8),b2=AL(rb+pc+1024),b3=AL(rb+pc+1032);
      for (;;) {
        u64 c0=AL(rb+pc),c1=AL(rb+pc+8),c2=AL(rb+pc+1024),c3=AL(rb+pc+1032);
        if (OK(a0,a1,a2,a3)) { v0=a0;v1=a1;v2=a2;v3=a3; break; }
        a0=AL(rb+pc);a1=AL(rb+pc+8);a2=AL(rb+pc+1024);a3=AL(rb+pc+1032);
        if (OK(b0,b1,b2,b3)) { v0=b0;v1=b1;v2=b2;v3=b3; break; }
        b0=AL(rb+pc);b1=AL(rb+pc+8);b2=AL(rb+pc+1024);b3=AL(rb+pc+1032);
        if (OK(c0,c1,c2,c3)) { v0=c0;v1=c1;v2=c2;v3=c3; break; }
        if (--budget < 0)    { v0=c0;v1=c1;v2=c2;v3=c3; break; }
      }
#undef OK
    }

    // stage remote lanes into LDS (local lanes already written by producers)
    char* lp = (char*)lds[t & 1];
    if (!loc01) { ulonglong2 a; a.x = v0; a.y = v1; *(ulonglong2*)(lp + pc) = a; }
    if (!loc23) { ulonglong2 a; a.x = v2; a.y = v3; *(ulonglong2*)(lp + pc + 1024) = a; }
    __syncthreads();

    floatx4 xv = {0.f, 0.f, 0.f, 0.f};
    if (vis) xv = *(const floatx4*)(X + t * VDIM + jb);

    // ---- MFMA: D[j][i] = sum_k W[j,k] r[i,k], 16 kk x (hi,lo)
    floatx4 aH = {0.f,0.f,0.f,0.f}, aL = {0.f,0.f,0.f,0.f};
#pragma unroll
    for (int kk = 0; kk < 16; ++kk) {
      half8 bh = *(const half8*)(lp + kk * 1024 + l * 16);
      aH = __builtin_amdgcn_mfma_f32_16x16x32_f16(wh[kk], bh, aH, 0, 0, 0);
      aL = __builtin_amdgcn_mfma_f32_16x16x32_f16(wl[kk], bh, aL, 0, 0, 0);
    }

    // ---- epilogue: combine, blend, tanh, tag, publish r(t+1)
    const bool last = (t == TSTEPS - 1);
    union { half4 h; u64 u; } pk;
#pragma unroll
    for (int v = 0; v < 4; ++v) {
      float u = aH[v] + aL[v] * 2.44140625e-4f + bv[v];
      const bool isdiag = diagHere && (lg * 4 + v == lr);
      if (vis && !isdiag) u = 0.5f * u + 0.5f * xv[v];
      if (last) {
        if (isdiag) out[16 * g + lr] = u;     // diag of U, pre-tanh
      } else {
        float au = fabsf(u);
        float e2 = __expf(-2.0f * au);
        float th = __fdividef(1.0f - e2, 1.0f + e2);
        pk.h[v] = (_Float16)copysignf(th, u);
      }
    }

    if (!last) {
      const u64 ntag = (u64)(((t + 1) >> 1) & 1) * TAGM;
      u64 val = (pk.u & ~TAGM) | ntag;
      // local short-circuit: own features directly into next-parity LDS
      union { u64 u; half4 h; } lv; lv.u = val;
      *(half4*)((_Float16*)lds[(t + 1) & 1] + so) = lv.h;
      // global publish for the other 3 slices (IC write-through)
      char* wbuf = (char*)rbase + (size_t)((t + 1) & 1) * (128 * 1024)
                 + (size_t)g * 16384;
      __hip_atomic_store((u64*)(wbuf + so * 2), val, __ATOMIC_RELAXED,
                         __HIP_MEMORY_SCOPE_AGENT);
    }
  }
}

extern "C" void kernel_launch(void* const* d_in, const int* in_sizes, int n_in,
                              void* d_out, int out_size, void* d_ws, size_t ws_size,
                              hipStream_t stream) {
  const float* X = (const float*)d_in[0];
  const float* W = (const float*)d_in[1];
  const float* b = (const float*)d_in[2];
  float* out = (float*)d_out;
  char* ws = (char*)d_ws;

  _Float16* WH = (_Float16*)(ws + WS_WH);
  _Float16* WL = (_Float16*)(ws + WS_WL);
  _Float16* rb = (_Float16*)(ws + WS_R);

  // parity-0 r: zeros (valid r(0), tag 0).  parity-1: 0x0101 (tag=1, invalid
  // for tau(1)=0).
  hipMemsetAsync(ws + WS_R, 0x00, 128 * 1024, stream);
  hipMemsetAsync(ws + WS_R + 128 * 1024, 0x01, 128 * 1024, stream);
  rnn_prep<<<128, 256, 0, stream>>>(W, WH, WL);
  rnn_main<<<32, 512, 0, stream>>>(X, b, WH, WL, rb, out);
}